// Round 4
// baseline (1206.113 us; speedup 1.0000x reference)
//
#include <hip/hip_runtime.h>
#include <float.h>

#define NS 1536
#define DD 64

// ws layout (float elements)
static const size_t OFF_A  = 0;                          // A = h_sat + b1: [1536][64]
static const size_t OFF_C2 = 98304;                      // C2 = h_uav transposed [16][1536][4]
static const size_t OFF_L  = 196608;                     // logits [1536][1536]
static const size_t OFF_AS = 196608 + (size_t)NS * NS;   // int assign [1536]
// top_idx (ushort, 1536*256 = 786432 B) ALIASES the A/C2 region (dead after kB).

// ---------------- Kernel A: first-layer projections ----------------
__global__ __launch_bounds__(64) void kA(const float* __restrict__ sat,
                                         const float* __restrict__ uav,
                                         const float* __restrict__ W1,
                                         const float* __restrict__ b1,
                                         float* __restrict__ A,
                                         float* __restrict__ C2) {
    const int row = blockIdx.x;
    const int d = threadIdx.x;
    float accA = b1[d];
    float accC = 0.f;
    const float* __restrict__ satr = sat + row * DD;
    const float* __restrict__ uavr = uav + row * DD;
#pragma unroll 8
    for (int k = 0; k < DD; ++k) {
        accA = fmaf(satr[k], W1[k * DD + d], accA);
        accC = fmaf(uavr[k], W1[(DD + k) * DD + d], accC);
    }
    A[row * DD + d] = accA;
    C2[((size_t)(d >> 2) * NS + row) * 4 + (d & 3)] = accC;
}

// ---------------- Kernel B: all-pairs logits ----------------
__global__ __launch_bounds__(256) void kB(const float* __restrict__ A,
                                          const float* __restrict__ C2,
                                          const float* __restrict__ W2,
                                          const float* __restrict__ b2,
                                          const float* __restrict__ W3,
                                          float* __restrict__ L) {
    const int lane = threadIdx.x & 63;
    const int wave = threadIdx.x >> 6;
    const int i = __builtin_amdgcn_readfirstlane(blockIdx.x * 4 + wave);
    const int jbase = blockIdx.y * 256;
    const float* __restrict__ Ar = A + (size_t)i * DD;

    float u[4][32];
#pragma unroll
    for (int o = 0; o < 32; ++o) {
        const float b = b2[o];
        u[0][o] = b; u[1][o] = b; u[2][o] = b; u[3][o] = b;
    }

    const float4* __restrict__ C2v = (const float4*)C2;

    for (int d4 = 0; d4 < 16; ++d4) {
        float c[4][4];
#pragma unroll
        for (int p = 0; p < 4; ++p) {
            const float4 t = C2v[(size_t)d4 * NS + jbase + p * 64 + lane];
            c[p][0] = t.x; c[p][1] = t.y; c[p][2] = t.z; c[p][3] = t.w;
        }
#pragma unroll
        for (int dd = 0; dd < 4; ++dd) {
            const float a = Ar[d4 * 4 + dd];
            const float v0 = fmaxf(a + c[0][dd], 0.f);
            const float v1 = fmaxf(a + c[1][dd], 0.f);
            const float v2 = fmaxf(a + c[2][dd], 0.f);
            const float v3 = fmaxf(a + c[3][dd], 0.f);
            const float* __restrict__ w2r = W2 + (d4 * 4 + dd) * 32;
#pragma unroll
            for (int o = 0; o < 32; ++o) {
                const float w = w2r[o];
                u[0][o] = fmaf(v0, w, u[0][o]);
                u[1][o] = fmaf(v1, w, u[1][o]);
                u[2][o] = fmaf(v2, w, u[2][o]);
                u[3][o] = fmaf(v3, w, u[3][o]);
            }
        }
    }

#pragma unroll
    for (int p = 0; p < 4; ++p) {
        float acc = 0.f;
#pragma unroll
        for (int o = 0; o < 32; ++o)
            acc = fmaf(fmaxf(u[p][o], 0.f), W3[o], acc);
        L[(size_t)i * NS + jbase + p * 64 + lane] = acc;
    }
}

// ---------------- Kernel C: per-row sorted top-256 via 16-bit radix ----------------
// Swizzled layout: rank r lives at top[row*256 + (r&63)*4 + (r>>6)] so kD's
// uint2-per-lane read gives lane l ranks {l, l+64, l+128, l+192}.
__global__ __launch_bounds__(256) void kC(const float* __restrict__ L,
                                          unsigned short* __restrict__ top) {
    __shared__ int hist[256];
    __shared__ int suff[256];
    __shared__ float cv[1024];
    __shared__ int ci[1024];
    __shared__ int s_cnt, s_B0, s_base, s_B1;
    const int t = threadIdx.x;
    const int row = blockIdx.x;
    const float* __restrict__ Lr = L + (size_t)row * NS;

    top[row * 256 + t] = 0xFFFFu;   // sentinel (degenerate rows -> kD fallback)

    hist[t] = 0;
    if (t == 0) s_cnt = 0;
    __syncthreads();

    unsigned ub[6]; float fv[6];
#pragma unroll
    for (int k = 0; k < 6; ++k) {
        const float x = Lr[t + 256 * k];
        fv[k] = x;
        unsigned b = __float_as_uint(x);
        b = (b & 0x80000000u) ? ~b : (b | 0x80000000u);
        ub[k] = b;
        atomicAdd(&hist[b >> 24], 1);
    }
    __syncthreads();

    suff[t] = hist[t];
    __syncthreads();
    for (int off = 1; off < 256; off <<= 1) {
        const int v = (t + off < 256) ? suff[t + off] : 0;
        __syncthreads();
        suff[t] += v;
        __syncthreads();
    }
    if (suff[t] >= 256 && (t == 255 || suff[t + 1] < 256)) {
        s_B0 = t;
        s_base = (t == 255) ? 0 : suff[t + 1];
    }
    __syncthreads();
    const unsigned B0 = (unsigned)s_B0;
    const int base = s_base;

    hist[t] = 0;
    __syncthreads();
#pragma unroll
    for (int k = 0; k < 6; ++k)
        if ((ub[k] >> 24) == B0) atomicAdd(&hist[(ub[k] >> 16) & 255], 1);
    __syncthreads();
    suff[t] = hist[t];
    __syncthreads();
    for (int off = 1; off < 256; off <<= 1) {
        const int v = (t + off < 256) ? suff[t + off] : 0;
        __syncthreads();
        suff[t] += v;
        __syncthreads();
    }
    const int need = 256 - base;
    if (suff[t] >= need && (t == 255 || suff[t + 1] < need)) s_B1 = t;
    __syncthreads();
    const unsigned B1 = (unsigned)s_B1;
    const int m = base + suff[B1];
    if (m > 1024) return;

#pragma unroll
    for (int k = 0; k < 6; ++k) {
        const unsigned hi = ub[k] >> 24;
        const unsigned mid = (ub[k] >> 16) & 255u;
        if (hi > B0 || (hi == B0 && mid >= B1)) {
            const int pos = atomicAdd(&s_cnt, 1);
            cv[pos] = fv[k];
            ci[pos] = t + 256 * k;
        }
    }
    __syncthreads();

    for (int e = t; e < m; e += 256) {
        const float v = cv[e]; const int id = ci[e];
        int r = 0;
        for (int s2 = 0; s2 < m; ++s2) {
            const float vs = cv[s2];
            if (vs > v || (vs == v && ci[s2] < id)) ++r;
        }
        if (r < 256) top[row * 256 + (r & 63) * 4 + (r >> 6)] = (unsigned short)id;
    }
}

// ---------------- Kernel D: sequential greedy (single wave) ----------------
// Proven ballot fast path + NEW register-resident fallback: the full L row for
// row i+2 is prefetched (coalesced, 6 x float4/lane, 2-slot ring refilled after
// each commit) so the ~1000 late-row fallbacks never touch global memory on the
// critical chain. Fallback = 6 LDS bitmask reads (live, packed used_b) + 24
// predicated compares + shuffle reduce (~700 cy vs ~1.5-1.6k before).
// Ring slot (i&1) == (q&1) is compile-time after the unrolled q-loop -> rv stays
// in registers (rule #20).
__global__ __launch_bounds__(64) void kD(const float* __restrict__ L,
                                         const unsigned short* __restrict__ top,
                                         int* __restrict__ assign) {
    __shared__ int used_s[NS];          // word flags (ballot-path prefetch reads)
    __shared__ int used_b[NS / 32];     // packed bit flags (fallback reads)
    __shared__ int assign_s[NS];
    const int lane = threadIdx.x;
    for (int k = lane; k < NS; k += 64) used_s[k] = 0;
    if (lane < NS / 32) used_b[lane] = 0;
    __syncthreads();

    const uint2* __restrict__ T = (const uint2*)top;   // T[row*64 + lane]
    const float4* __restrict__ L4 = (const float4*)L;  // row r: L4[r*384 + lane + 64*m]

    uint2 buf[16];           // rows g..g+15
#pragma unroll
    for (int k = 0; k < 16; ++k) buf[k] = T[k * 64 + lane];

    // L-row ring: slot p holds row (current i with i&1==p); init rows 0,1.
    float4 rv[2][6];
#pragma unroll
    for (int m = 0; m < 6; ++m) rv[0][m] = L4[(size_t)0 * 384 + lane + 64 * m];
#pragma unroll
    for (int m = 0; m < 6; ++m) rv[1][m] = L4[(size_t)1 * 384 + lane + 64 * m];

    int f0 = 0, f1 = 0, f2 = 0, f3 = 0;   // row-0 flags: nothing used yet
    int jprev = -1;

    for (int g = 0; g < NS; g += 8) {
        // issue T loads for rows g+16..g+23 (consumed 2 groups from now)
        uint2 nb[8];
#pragma unroll
        for (int k = 0; k < 8; ++k) {
            int r = g + 16 + k;
            r = (r < NS) ? r : (NS - 1);
            nb[k] = T[r * 64 + lane];
        }

#pragma unroll
        for (int q = 0; q < 8; ++q) {
            const int i = g + q;

            // prefetch used-flags for row i+1 (candidates resident in buf[q+1])
            const uint2 pn = buf[q + 1];
            const int n0 = (int)(pn.x & 0xFFFFu), n1 = (int)(pn.x >> 16);
            const int n2 = (int)(pn.y & 0xFFFFu), n3 = (int)(pn.y >> 16);
            const int g0 = used_s[n0 < NS ? n0 : 0];
            const int g1 = used_s[n1 < NS ? n1 : 0];
            const int g2 = used_s[n2 < NS ? n2 : 0];
            const int g3 = used_s[n3 < NS ? n3 : 0];

            const uint2 pc = buf[q];
            const int c0 = (int)(pc.x & 0xFFFFu), c1 = (int)(pc.x >> 16);
            const int c2 = (int)(pc.y & 0xFFFFu), c3 = (int)(pc.y >> 16);
            const bool a0 = (c0 < NS) && (f0 == 0) && (c0 != jprev);
            const bool a1 = (c1 < NS) && (f1 == 0) && (c1 != jprev);
            const bool a2 = (c2 < NS) && (f2 == 0) && (c2 != jprev);
            const bool a3 = (c3 < NS) && (f3 == 0) && (c3 != jprev);
            const unsigned long long b0 = __ballot(a0);
            const unsigned long long b1 = __ballot(a1);
            const unsigned long long b2 = __ballot(a2);
            const unsigned long long b3 = __ballot(a3);

            int j;
            if (b0)      j = __builtin_amdgcn_readlane(c0, __ffsll(b0) - 1);
            else if (b1) j = __builtin_amdgcn_readlane(c1, __ffsll(b1) - 1);
            else if (b2) j = __builtin_amdgcn_readlane(c2, __ffsll(b2) - 1);
            else if (b3) j = __builtin_amdgcn_readlane(c3, __ffsll(b3) - 1);
            else {
                // ---- register-resident masked argmax over full row i ----
                // values already in rv[q&1][*]; flags live from packed used_b.
                const int bsh = (lane & 7) * 4;   // bit base for sub=0..3
                int w[6];
#pragma unroll
                for (int m = 0; m < 6; ++m) w[m] = used_b[(lane >> 3) + 8 * m];
                float bv = -FLT_MAX; int bi = NS;
#pragma unroll
                for (int m = 0; m < 6; ++m) {
                    const float4 q4 = rv[q & 1][m];
                    const int colb = 4 * lane + 256 * m;
                    const float vs[4] = {q4.x, q4.y, q4.z, q4.w};
#pragma unroll
                    for (int sub = 0; sub < 4; ++sub) {
                        const int col = colb + sub;
                        const bool free_ = (((unsigned)w[m] >> (bsh + sub)) & 1u) == 0u;
                        const float v = vs[sub];
                        if (free_ && (v > bv || (v == bv && col < bi))) {
                            bv = v; bi = col;
                        }
                    }
                }
#pragma unroll
                for (int o = 32; o >= 1; o >>= 1) {
                    const float ov = __shfl_xor(bv, o);
                    const int oi = __shfl_xor(bi, o);
                    if (ov > bv || (ov == bv && oi < bi)) { bv = ov; bi = oi; }
                }
                j = bi;
            }
            if (lane == 0) {
                used_s[j] = 1;
                used_b[j >> 5] |= (1 << (j & 31));
                assign_s[i] = j;
            }
            jprev = j;
            f0 = g0; f1 = g1; f2 = g2; f3 = g3;

            // refill ring slot (q&1) with row i+2 (consumed two rows from now)
            {
                const int r2 = (i + 2 < NS) ? (i + 2) : (NS - 1);
#pragma unroll
                for (int m = 0; m < 6; ++m)
                    rv[q & 1][m] = L4[(size_t)r2 * 384 + lane + 64 * m];
            }
        }

        // rotate: waits only for loads issued ~8 rows ago (fully landed)
#pragma unroll
        for (int k = 0; k < 8; ++k) buf[k] = buf[k + 8];
#pragma unroll
        for (int k = 0; k < 8; ++k) buf[k + 8] = nb[k];
    }

    for (int k = lane; k < NS; k += 64) assign[k] = assign_s[k];
}

// ---------------- Kernel E: emit [1536][2][64] output ----------------
__global__ __launch_bounds__(128) void kE(const float* __restrict__ sat,
                                          const float* __restrict__ uav,
                                          const int* __restrict__ assign,
                                          float* __restrict__ out) {
    const int i = blockIdx.x;
    const int t = threadIdx.x;
    if (t < 64) out[(size_t)i * 128 + t] = sat[(size_t)i * DD + t];
    else        out[(size_t)i * 128 + t] = uav[(size_t)assign[i] * DD + (t - 64)];
}

extern "C" void kernel_launch(void* const* d_in, const int* in_sizes, int n_in,
                              void* d_out, int out_size, void* d_ws, size_t ws_size,
                              hipStream_t stream) {
    const float* sat = (const float*)d_in[0];
    const float* uav = (const float*)d_in[1];
    const float* W1  = (const float*)d_in[2];
    const float* b1  = (const float*)d_in[3];
    const float* W2  = (const float*)d_in[4];
    const float* b2  = (const float*)d_in[5];
    const float* W3  = (const float*)d_in[6];
    // d_in[7] = b3: sigmoid(x+b3) monotone in x — argmax unchanged.

    float* ws = (float*)d_ws;
    float* A   = ws + OFF_A;
    float* C2  = ws + OFF_C2;
    float* L   = ws + OFF_L;
    int* assign = (int*)(ws + OFF_AS);
    unsigned short* top = (unsigned short*)(ws + OFF_A);  // aliases A/C2 (dead after kB)

    hipLaunchKernelGGL(kA, dim3(NS), dim3(64), 0, stream, sat, uav, W1, b1, A, C2);
    hipLaunchKernelGGL(kB, dim3(NS / 4, NS / 256), dim3(256), 0, stream,
                       A, C2, W2, b2, W3, L);
    hipLaunchKernelGGL(kC, dim3(NS), dim3(256), 0, stream, L, top);
    hipLaunchKernelGGL(kD, dim3(1), dim3(64), 0, stream, L, top, assign);
    hipLaunchKernelGGL(kE, dim3(NS), dim3(128), 0, stream, sat, uav, assign,
                       (float*)d_out);
}

// Round 5
// 1072.118 us; speedup vs baseline: 1.1250x; 1.1250x over previous
//
#include <hip/hip_runtime.h>
#include <float.h>

#define NS 1536
#define DD 64

// ws layout (float elements)
static const size_t OFF_A  = 0;                          // A = h_sat + b1: [1536][64]
static const size_t OFF_C2 = 98304;                      // C2 = h_uav transposed [16][1536][4]
static const size_t OFF_L  = 196608;                     // logits [1536][1536]
static const size_t OFF_AS = 196608 + (size_t)NS * NS;   // int assign [1536]
// top_idx (ushort, 1536*256 = 786432 B) ALIASES the A/C2 region (dead after kB).

// ---------------- Kernel A: first-layer projections ----------------
__global__ __launch_bounds__(64) void kA(const float* __restrict__ sat,
                                         const float* __restrict__ uav,
                                         const float* __restrict__ W1,
                                         const float* __restrict__ b1,
                                         float* __restrict__ A,
                                         float* __restrict__ C2) {
    const int row = blockIdx.x;
    const int d = threadIdx.x;
    float accA = b1[d];
    float accC = 0.f;
    const float* __restrict__ satr = sat + row * DD;
    const float* __restrict__ uavr = uav + row * DD;
#pragma unroll 8
    for (int k = 0; k < DD; ++k) {
        accA = fmaf(satr[k], W1[k * DD + d], accA);
        accC = fmaf(uavr[k], W1[(DD + k) * DD + d], accC);
    }
    A[row * DD + d] = accA;
    C2[((size_t)(d >> 2) * NS + row) * 4 + (d & 3)] = accC;
}

// ---------------- Kernel B: all-pairs logits ----------------
__global__ __launch_bounds__(256) void kB(const float* __restrict__ A,
                                          const float* __restrict__ C2,
                                          const float* __restrict__ W2,
                                          const float* __restrict__ b2,
                                          const float* __restrict__ W3,
                                          float* __restrict__ L) {
    const int lane = threadIdx.x & 63;
    const int wave = threadIdx.x >> 6;
    const int i = __builtin_amdgcn_readfirstlane(blockIdx.x * 4 + wave);
    const int jbase = blockIdx.y * 256;
    const float* __restrict__ Ar = A + (size_t)i * DD;

    float u[4][32];
#pragma unroll
    for (int o = 0; o < 32; ++o) {
        const float b = b2[o];
        u[0][o] = b; u[1][o] = b; u[2][o] = b; u[3][o] = b;
    }

    const float4* __restrict__ C2v = (const float4*)C2;

    for (int d4 = 0; d4 < 16; ++d4) {
        float c[4][4];
#pragma unroll
        for (int p = 0; p < 4; ++p) {
            const float4 t = C2v[(size_t)d4 * NS + jbase + p * 64 + lane];
            c[p][0] = t.x; c[p][1] = t.y; c[p][2] = t.z; c[p][3] = t.w;
        }
#pragma unroll
        for (int dd = 0; dd < 4; ++dd) {
            const float a = Ar[d4 * 4 + dd];
            const float v0 = fmaxf(a + c[0][dd], 0.f);
            const float v1 = fmaxf(a + c[1][dd], 0.f);
            const float v2 = fmaxf(a + c[2][dd], 0.f);
            const float v3 = fmaxf(a + c[3][dd], 0.f);
            const float* __restrict__ w2r = W2 + (d4 * 4 + dd) * 32;
#pragma unroll
            for (int o = 0; o < 32; ++o) {
                const float w = w2r[o];
                u[0][o] = fmaf(v0, w, u[0][o]);
                u[1][o] = fmaf(v1, w, u[1][o]);
                u[2][o] = fmaf(v2, w, u[2][o]);
                u[3][o] = fmaf(v3, w, u[3][o]);
            }
        }
    }

#pragma unroll
    for (int p = 0; p < 4; ++p) {
        float acc = 0.f;
#pragma unroll
        for (int o = 0; o < 32; ++o)
            acc = fmaf(fmaxf(u[p][o], 0.f), W3[o], acc);
        L[(size_t)i * NS + jbase + p * 64 + lane] = acc;
    }
}

// ---------------- Kernel C: per-row sorted top-256 via 16-bit radix ----------------
// Swizzled layout: rank r lives at top[row*256 + (r&63)*4 + (r>>6)] so kD's
// uint2-per-lane read gives lane l ranks {l, l+64, l+128, l+192}.
__global__ __launch_bounds__(256) void kC(const float* __restrict__ L,
                                          unsigned short* __restrict__ top) {
    __shared__ int hist[256];
    __shared__ int suff[256];
    __shared__ float cv[1024];
    __shared__ int ci[1024];
    __shared__ int s_cnt, s_B0, s_base, s_B1;
    const int t = threadIdx.x;
    const int row = blockIdx.x;
    const float* __restrict__ Lr = L + (size_t)row * NS;

    top[row * 256 + t] = 0xFFFFu;   // sentinel (degenerate rows -> kD fallback)

    hist[t] = 0;
    if (t == 0) s_cnt = 0;
    __syncthreads();

    unsigned ub[6]; float fv[6];
#pragma unroll
    for (int k = 0; k < 6; ++k) {
        const float x = Lr[t + 256 * k];
        fv[k] = x;
        unsigned b = __float_as_uint(x);
        b = (b & 0x80000000u) ? ~b : (b | 0x80000000u);
        ub[k] = b;
        atomicAdd(&hist[b >> 24], 1);
    }
    __syncthreads();

    suff[t] = hist[t];
    __syncthreads();
    for (int off = 1; off < 256; off <<= 1) {
        const int v = (t + off < 256) ? suff[t + off] : 0;
        __syncthreads();
        suff[t] += v;
        __syncthreads();
    }
    if (suff[t] >= 256 && (t == 255 || suff[t + 1] < 256)) {
        s_B0 = t;
        s_base = (t == 255) ? 0 : suff[t + 1];
    }
    __syncthreads();
    const unsigned B0 = (unsigned)s_B0;
    const int base = s_base;

    hist[t] = 0;
    __syncthreads();
#pragma unroll
    for (int k = 0; k < 6; ++k)
        if ((ub[k] >> 24) == B0) atomicAdd(&hist[(ub[k] >> 16) & 255], 1);
    __syncthreads();
    suff[t] = hist[t];
    __syncthreads();
    for (int off = 1; off < 256; off <<= 1) {
        const int v = (t + off < 256) ? suff[t + off] : 0;
        __syncthreads();
        suff[t] += v;
        __syncthreads();
    }
    const int need = 256 - base;
    if (suff[t] >= need && (t == 255 || suff[t + 1] < need)) s_B1 = t;
    __syncthreads();
    const unsigned B1 = (unsigned)s_B1;
    const int m = base + suff[B1];
    if (m > 1024) return;

#pragma unroll
    for (int k = 0; k < 6; ++k) {
        const unsigned hi = ub[k] >> 24;
        const unsigned mid = (ub[k] >> 16) & 255u;
        if (hi > B0 || (hi == B0 && mid >= B1)) {
            const int pos = atomicAdd(&s_cnt, 1);
            cv[pos] = fv[k];
            ci[pos] = t + 256 * k;
        }
    }
    __syncthreads();

    for (int e = t; e < m; e += 256) {
        const float v = cv[e]; const int id = ci[e];
        int r = 0;
        for (int s2 = 0; s2 < m; ++s2) {
            const float vs = cv[s2];
            if (vs > v || (vs == v && ci[s2] < id)) ++r;
        }
        if (r < 256) top[row * 256 + (r & 63) * 4 + (r >> 6)] = (unsigned short)id;
    }
}

// ---------------- Kernel D: sequential greedy (single wave) ----------------
// Round-3 structure (828us) + predicted one-row-ahead fallback prefetch:
// row i+1's candidate used-flags (g0..g3) are already read at row i; if no
// candidate is free (conservative: flags monotone, jprev only removes), row
// i+1 WILL fall back. Then issue its U_s gather (16 x idx+val into parity
// registers) at the top of row i -> one full row (~600-1000cy) of latency
// cover, WAW-free (slot consumed one row earlier). Fast consume: uniform
// c-gate on issue-time mU + live used_s filter + shuffle reduce, no global
// latency on the chain. mU>1024 rows and prediction misses use the old slow
// chunked scan.
__global__ __launch_bounds__(64) void kD(const float* __restrict__ L,
                                         const unsigned short* __restrict__ top,
                                         int* __restrict__ assign) {
    __shared__ int used_s[NS];
    __shared__ int assign_s[NS];
    __shared__ unsigned short U_s[NS];
    const int lane = threadIdx.x;
    for (int k = lane; k < NS; k += 64) used_s[k] = 0;
    __syncthreads();

    const uint2* __restrict__ T = (const uint2*)top;   // T[row*64 + lane]

    uint2 buf[16];           // rows g..g+15
#pragma unroll
    for (int k = 0; k < 16; ++k) buf[k] = T[k * 64 + lane];

    int f0 = 0, f1 = 0, f2 = 0, f3 = 0;   // row-0 flags: nothing used yet
    int jprev = -1;
    int mU = NS;

    // predicted-prefetch slots (parity by row index; q compile-time -> regs)
    float sval[2][16];
    int   sidx[2][16];
    int   sMU[2]    = {0, 0};
    int   svalid[2] = {0, 0};

    for (int g = 0; g < NS; g += 8) {
        // ---- rebuild compact unused list every 64 rows ----
        if ((g & 63) == 0) {
            int fl[24];
#pragma unroll
            for (int k = 0; k < 24; ++k) fl[k] = used_s[lane + (k << 6)];
            int cnt = 0;
#pragma unroll
            for (int k = 0; k < 24; ++k) cnt += (fl[k] == 0);
            int incl = cnt;
#pragma unroll
            for (int o = 1; o < 64; o <<= 1) {
                const int v = __shfl_up(incl, o);
                if (lane >= o) incl += v;
            }
            int pos = incl - cnt;   // exclusive prefix
#pragma unroll
            for (int k = 0; k < 24; ++k) {
                if (fl[k] == 0) { U_s[pos] = (unsigned short)(lane + (k << 6)); ++pos; }
            }
            mU = __builtin_amdgcn_readlane(incl, 63);
            // single wave: LDS ops in-order, no barrier needed
        }

        // issue T loads for rows g+16..g+23 (consumed 2 groups from now)
        uint2 nb[8];
#pragma unroll
        for (int k = 0; k < 8; ++k) {
            int r = g + 16 + k;
            r = (r < NS) ? r : (NS - 1);
            nb[k] = T[r * 64 + lane];
        }

#pragma unroll
        for (int q = 0; q < 8; ++q) {
            const int i = g + q;
            const int pq = q & 1;          // slot parity of row i
            const int pn = (q + 1) & 1;    // slot parity of row i+1

            // prefetch used-flags for row i+1 (candidates resident in buf[q+1])
            const uint2 pnx = buf[q + 1];
            const int n0 = (int)(pnx.x & 0xFFFFu), n1 = (int)(pnx.x >> 16);
            const int n2 = (int)(pnx.y & 0xFFFFu), n3 = (int)(pnx.y >> 16);
            const int g0 = used_s[n0 < NS ? n0 : 0];
            const int g1 = used_s[n1 < NS ? n1 : 0];
            const int g2 = used_s[n2 < NS ? n2 : 0];
            const int g3 = used_s[n3 < NS ? n3 : 0];

            // ---- predict fallback for row i+1; prefetch its candidates ----
            const bool anyfree = (n0 < NS && g0 == 0) || (n1 < NS && g1 == 0) ||
                                 (n2 < NS && g2 == 0) || (n3 < NS && g3 == 0);
            const unsigned long long pball = __ballot(anyfree);
            int nv = 0;
            if (pball == 0ULL && (i + 1 < NS) && mU <= 1024) {
                nv = 1;
                sMU[pn] = mU;
                const float* __restrict__ Lr1 = L + (size_t)(i + 1) * NS;
#pragma unroll
                for (int c = 0; c < 16; ++c) {
                    if ((c << 6) < mU) {          // wave-uniform chunk gate
                        const int id = (int)U_s[lane + (c << 6)];
                        sidx[pn][c] = id;
                        sval[pn][c] = Lr1[id];
                    }
                }
            }
            svalid[pn] = nv;

            const uint2 pc = buf[q];
            const int c0 = (int)(pc.x & 0xFFFFu), c1 = (int)(pc.x >> 16);
            const int c2 = (int)(pc.y & 0xFFFFu), c3 = (int)(pc.y >> 16);
            const bool a0 = (c0 < NS) && (f0 == 0) && (c0 != jprev);
            const bool a1 = (c1 < NS) && (f1 == 0) && (c1 != jprev);
            const bool a2 = (c2 < NS) && (f2 == 0) && (c2 != jprev);
            const bool a3 = (c3 < NS) && (f3 == 0) && (c3 != jprev);
            const unsigned long long b0 = __ballot(a0);
            const unsigned long long b1 = __ballot(a1);
            const unsigned long long b2 = __ballot(a2);
            const unsigned long long b3 = __ballot(a3);

            int j;
            if (b0)      j = __builtin_amdgcn_readlane(c0, __ffsll(b0) - 1);
            else if (b1) j = __builtin_amdgcn_readlane(c1, __ffsll(b1) - 1);
            else if (b2) j = __builtin_amdgcn_readlane(c2, __ffsll(b2) - 1);
            else if (b3) j = __builtin_amdgcn_readlane(c3, __ffsll(b3) - 1);
            else {
                j = NS;
                if (svalid[pq]) {
                    // ---- fast consume: values already in registers ----
                    float bv = -FLT_MAX; int bi = NS;
#pragma unroll
                    for (int c = 0; c < 16; ++c) {
                        if ((c << 6) < sMU[pq]) {   // wave-uniform
                            const int id = sidx[pq][c];
                            const int uf = used_s[id];   // live filter
                            const float v = sval[pq][c];
                            if (uf == 0 && (v > bv || (v == bv && id < bi))) {
                                bv = v; bi = id;
                            }
                        }
                    }
#pragma unroll
                    for (int o = 32; o >= 1; o >>= 1) {
                        const float ov = __shfl_xor(bv, o);
                        const int oi = __shfl_xor(bi, o);
                        if (ov > bv || (ov == bv && oi < bi)) { bv = ov; bi = oi; }
                    }
                    j = bi;
                }
                if (j >= NS) {
                    // ---- slow path: chunked scan over current U_s ----
                    const float* __restrict__ Lr = L + (size_t)i * NS;
                    float bv = -FLT_MAX; int bi = NS;
                    for (int kbase = 0; kbase < mU; kbase += 512) {
                        int idx[8]; int flc[8]; float vv[8];
#pragma unroll
                        for (int c = 0; c < 8; ++c) {
                            const int k = kbase + lane + (c << 6);
                            idx[c] = (k < mU) ? (int)U_s[k] : 0;
                        }
#pragma unroll
                        for (int c = 0; c < 8; ++c) flc[c] = used_s[idx[c]];
#pragma unroll
                        for (int c = 0; c < 8; ++c) vv[c] = Lr[idx[c]];
#pragma unroll
                        for (int c = 0; c < 8; ++c) {
                            const int k = kbase + lane + (c << 6);
                            if (k < mU && flc[c] == 0 &&
                                (vv[c] > bv || (vv[c] == bv && idx[c] < bi))) {
                                bv = vv[c]; bi = idx[c];
                            }
                        }
                    }
#pragma unroll
                    for (int o = 32; o >= 1; o >>= 1) {
                        const float ov = __shfl_xor(bv, o);
                        const int oi = __shfl_xor(bi, o);
                        if (ov > bv || (ov == bv && oi < bi)) { bv = ov; bi = oi; }
                    }
                    j = bi;
                }
            }
            if (lane == 0) { used_s[j] = 1; assign_s[i] = j; }
            jprev = j;
            f0 = g0; f1 = g1; f2 = g2; f3 = g3;
        }

        // rotate: waits only for loads issued ~8 rows ago (fully landed)
#pragma unroll
        for (int k = 0; k < 8; ++k) buf[k] = buf[k + 8];
#pragma unroll
        for (int k = 0; k < 8; ++k) buf[k + 8] = nb[k];
    }

    for (int k = lane; k < NS; k += 64) assign[k] = assign_s[k];
}

// ---------------- Kernel E: emit [1536][2][64] output ----------------
__global__ __launch_bounds__(128) void kE(const float* __restrict__ sat,
                                          const float* __restrict__ uav,
                                          const int* __restrict__ assign,
                                          float* __restrict__ out) {
    const int i = blockIdx.x;
    const int t = threadIdx.x;
    if (t < 64) out[(size_t)i * 128 + t] = sat[(size_t)i * DD + t];
    else        out[(size_t)i * 128 + t] = uav[(size_t)assign[i] * DD + (t - 64)];
}

extern "C" void kernel_launch(void* const* d_in, const int* in_sizes, int n_in,
                              void* d_out, int out_size, void* d_ws, size_t ws_size,
                              hipStream_t stream) {
    const float* sat = (const float*)d_in[0];
    const float* uav = (const float*)d_in[1];
    const float* W1  = (const float*)d_in[2];
    const float* b1  = (const float*)d_in[3];
    const float* W2  = (const float*)d_in[4];
    const float* b2  = (const float*)d_in[5];
    const float* W3  = (const float*)d_in[6];
    // d_in[7] = b3: sigmoid(x+b3) monotone in x — argmax unchanged.

    float* ws = (float*)d_ws;
    float* A   = ws + OFF_A;
    float* C2  = ws + OFF_C2;
    float* L   = ws + OFF_L;
    int* assign = (int*)(ws + OFF_AS);
    unsigned short* top = (unsigned short*)(ws + OFF_A);  // aliases A/C2 (dead after kB)

    hipLaunchKernelGGL(kA, dim3(NS), dim3(64), 0, stream, sat, uav, W1, b1, A, C2);
    hipLaunchKernelGGL(kB, dim3(NS / 4, NS / 256), dim3(256), 0, stream,
                       A, C2, W2, b2, W3, L);
    hipLaunchKernelGGL(kC, dim3(NS), dim3(256), 0, stream, L, top);
    hipLaunchKernelGGL(kD, dim3(1), dim3(64), 0, stream, L, top, assign);
    hipLaunchKernelGGL(kE, dim3(NS), dim3(128), 0, stream, sat, uav, assign,
                       (float*)d_out);
}

// Round 6
// 871.913 us; speedup vs baseline: 1.3833x; 1.2296x over previous
//
#include <hip/hip_runtime.h>
#include <float.h>

#define NS 1536
#define DD 64

// ws layout (float elements)
static const size_t OFF_A  = 0;                          // A = h_sat + b1: [1536][64]
static const size_t OFF_C2 = 98304;                      // C2 = h_uav transposed [16][1536][4]
static const size_t OFF_L  = 196608;                     // logits [1536][1536]
static const size_t OFF_AS = 196608 + (size_t)NS * NS;   // int assign [1536]
// top_idx (ushort, 1536*256 = 786432 B) ALIASES the A/C2 region (dead after kB).

// ---------------- Kernel A: first-layer projections ----------------
__global__ __launch_bounds__(64) void kA(const float* __restrict__ sat,
                                         const float* __restrict__ uav,
                                         const float* __restrict__ W1,
                                         const float* __restrict__ b1,
                                         float* __restrict__ A,
                                         float* __restrict__ C2) {
    const int row = blockIdx.x;
    const int d = threadIdx.x;
    float accA = b1[d];
    float accC = 0.f;
    const float* __restrict__ satr = sat + row * DD;
    const float* __restrict__ uavr = uav + row * DD;
#pragma unroll 8
    for (int k = 0; k < DD; ++k) {
        accA = fmaf(satr[k], W1[k * DD + d], accA);
        accC = fmaf(uavr[k], W1[(DD + k) * DD + d], accC);
    }
    A[row * DD + d] = accA;
    C2[((size_t)(d >> 2) * NS + row) * 4 + (d & 3)] = accC;
}

// ---------------- Kernel B: all-pairs logits ----------------
__global__ __launch_bounds__(256) void kB(const float* __restrict__ A,
                                          const float* __restrict__ C2,
                                          const float* __restrict__ W2,
                                          const float* __restrict__ b2,
                                          const float* __restrict__ W3,
                                          float* __restrict__ L) {
    const int lane = threadIdx.x & 63;
    const int wave = threadIdx.x >> 6;
    const int i = __builtin_amdgcn_readfirstlane(blockIdx.x * 4 + wave);
    const int jbase = blockIdx.y * 256;
    const float* __restrict__ Ar = A + (size_t)i * DD;

    float u[4][32];
#pragma unroll
    for (int o = 0; o < 32; ++o) {
        const float b = b2[o];
        u[0][o] = b; u[1][o] = b; u[2][o] = b; u[3][o] = b;
    }

    const float4* __restrict__ C2v = (const float4*)C2;

    for (int d4 = 0; d4 < 16; ++d4) {
        float c[4][4];
#pragma unroll
        for (int p = 0; p < 4; ++p) {
            const float4 t = C2v[(size_t)d4 * NS + jbase + p * 64 + lane];
            c[p][0] = t.x; c[p][1] = t.y; c[p][2] = t.z; c[p][3] = t.w;
        }
#pragma unroll
        for (int dd = 0; dd < 4; ++dd) {
            const float a = Ar[d4 * 4 + dd];
            const float v0 = fmaxf(a + c[0][dd], 0.f);
            const float v1 = fmaxf(a + c[1][dd], 0.f);
            const float v2 = fmaxf(a + c[2][dd], 0.f);
            const float v3 = fmaxf(a + c[3][dd], 0.f);
            const float* __restrict__ w2r = W2 + (d4 * 4 + dd) * 32;
#pragma unroll
            for (int o = 0; o < 32; ++o) {
                const float w = w2r[o];
                u[0][o] = fmaf(v0, w, u[0][o]);
                u[1][o] = fmaf(v1, w, u[1][o]);
                u[2][o] = fmaf(v2, w, u[2][o]);
                u[3][o] = fmaf(v3, w, u[3][o]);
            }
        }
    }

#pragma unroll
    for (int p = 0; p < 4; ++p) {
        float acc = 0.f;
#pragma unroll
        for (int o = 0; o < 32; ++o)
            acc = fmaf(fmaxf(u[p][o], 0.f), W3[o], acc);
        L[(size_t)i * NS + jbase + p * 64 + lane] = acc;
    }
}

// ---------------- Kernel C: per-row sorted top-256 via 16-bit radix ----------------
// Swizzled layout: rank r lives at top[row*256 + (r&63)*4 + (r>>6)] so kD's
// uint2-per-lane read gives lane l ranks {l, l+64, l+128, l+192}.
__global__ __launch_bounds__(256) void kC(const float* __restrict__ L,
                                          unsigned short* __restrict__ top) {
    __shared__ int hist[256];
    __shared__ int suff[256];
    __shared__ float cv[1024];
    __shared__ int ci[1024];
    __shared__ int s_cnt, s_B0, s_base, s_B1;
    const int t = threadIdx.x;
    const int row = blockIdx.x;
    const float* __restrict__ Lr = L + (size_t)row * NS;

    top[row * 256 + t] = 0xFFFFu;   // sentinel (degenerate rows -> kD fallback)

    hist[t] = 0;
    if (t == 0) s_cnt = 0;
    __syncthreads();

    unsigned ub[6]; float fv[6];
#pragma unroll
    for (int k = 0; k < 6; ++k) {
        const float x = Lr[t + 256 * k];
        fv[k] = x;
        unsigned b = __float_as_uint(x);
        b = (b & 0x80000000u) ? ~b : (b | 0x80000000u);
        ub[k] = b;
        atomicAdd(&hist[b >> 24], 1);
    }
    __syncthreads();

    suff[t] = hist[t];
    __syncthreads();
    for (int off = 1; off < 256; off <<= 1) {
        const int v = (t + off < 256) ? suff[t + off] : 0;
        __syncthreads();
        suff[t] += v;
        __syncthreads();
    }
    if (suff[t] >= 256 && (t == 255 || suff[t + 1] < 256)) {
        s_B0 = t;
        s_base = (t == 255) ? 0 : suff[t + 1];
    }
    __syncthreads();
    const unsigned B0 = (unsigned)s_B0;
    const int base = s_base;

    hist[t] = 0;
    __syncthreads();
#pragma unroll
    for (int k = 0; k < 6; ++k)
        if ((ub[k] >> 24) == B0) atomicAdd(&hist[(ub[k] >> 16) & 255], 1);
    __syncthreads();
    suff[t] = hist[t];
    __syncthreads();
    for (int off = 1; off < 256; off <<= 1) {
        const int v = (t + off < 256) ? suff[t + off] : 0;
        __syncthreads();
        suff[t] += v;
        __syncthreads();
    }
    const int need = 256 - base;
    if (suff[t] >= need && (t == 255 || suff[t + 1] < need)) s_B1 = t;
    __syncthreads();
    const unsigned B1 = (unsigned)s_B1;
    const int m = base + suff[B1];
    if (m > 1024) return;

#pragma unroll
    for (int k = 0; k < 6; ++k) {
        const unsigned hi = ub[k] >> 24;
        const unsigned mid = (ub[k] >> 16) & 255u;
        if (hi > B0 || (hi == B0 && mid >= B1)) {
            const int pos = atomicAdd(&s_cnt, 1);
            cv[pos] = fv[k];
            ci[pos] = t + 256 * k;
        }
    }
    __syncthreads();

    for (int e = t; e < m; e += 256) {
        const float v = cv[e]; const int id = ci[e];
        int r = 0;
        for (int s2 = 0; s2 < m; ++s2) {
            const float vs = cv[s2];
            if (vs > v || (vs == v && ci[s2] < id)) ++r;
        }
        if (r < 256) top[row * 256 + (r & 63) * 4 + (r >> 6)] = (unsigned short)id;
    }
}

// Wave-wide max of a u32 via DPP (pure VALU, ~4-8cy/stage vs ~60cy/bpermute).
// bound_ctrl=true fills invalid source lanes with 0 -> 0 must be a safe
// identity (all our keys are > 0). Lane 63 holds the wave max afterwards.
__device__ __forceinline__ unsigned wave_max_u32_dpp(unsigned x) {
    unsigned t;
    t = (unsigned)__builtin_amdgcn_update_dpp(0, (int)x, 0x111, 0xF, 0xF, true); // row_shr:1
    x = x > t ? x : t;
    t = (unsigned)__builtin_amdgcn_update_dpp(0, (int)x, 0x112, 0xF, 0xF, true); // row_shr:2
    x = x > t ? x : t;
    t = (unsigned)__builtin_amdgcn_update_dpp(0, (int)x, 0x114, 0xF, 0xF, true); // row_shr:4
    x = x > t ? x : t;
    t = (unsigned)__builtin_amdgcn_update_dpp(0, (int)x, 0x118, 0xF, 0xF, true); // row_shr:8
    x = x > t ? x : t;
    t = (unsigned)__builtin_amdgcn_update_dpp(0, (int)x, 0x142, 0xF, 0xF, true); // row_bcast:15
    x = x > t ? x : t;
    t = (unsigned)__builtin_amdgcn_update_dpp(0, (int)x, 0x143, 0xF, 0xF, true); // row_bcast:31
    x = x > t ? x : t;
    return x;
}

// ---------------- Kernel D: sequential greedy (single wave) ----------------
// Round-3 structure (828us) with the bpermute shuffle-argmax replaced by a
// two-phase DPP reduction (~150cy vs ~500cy): phase 1 = wave max of the
// sortable-u32 key of bv; phase 2 = wave max of (NS - bi) among key==max
// lanes -> min index tiebreak, exactly argmax first-occurrence semantics.
__global__ __launch_bounds__(64) void kD(const float* __restrict__ L,
                                         const unsigned short* __restrict__ top,
                                         int* __restrict__ assign) {
    __shared__ int used_s[NS];
    __shared__ int assign_s[NS];
    __shared__ unsigned short U_s[NS];
    const int lane = threadIdx.x;
    for (int k = lane; k < NS; k += 64) used_s[k] = 0;
    __syncthreads();

    const uint2* __restrict__ T = (const uint2*)top;   // T[row*64 + lane]

    uint2 buf[16];           // rows g..g+15
#pragma unroll
    for (int k = 0; k < 16; ++k) buf[k] = T[k * 64 + lane];

    int f0 = 0, f1 = 0, f2 = 0, f3 = 0;   // row-0 flags: nothing used yet
    int jprev = -1;
    int mU = NS;

    for (int g = 0; g < NS; g += 8) {
        // ---- rebuild compact unused list every 64 rows ----
        if ((g & 63) == 0) {
            int fl[24];
#pragma unroll
            for (int k = 0; k < 24; ++k) fl[k] = used_s[lane + (k << 6)];
            int cnt = 0;
#pragma unroll
            for (int k = 0; k < 24; ++k) cnt += (fl[k] == 0);
            int incl = cnt;
#pragma unroll
            for (int o = 1; o < 64; o <<= 1) {
                const int v = __shfl_up(incl, o);
                if (lane >= o) incl += v;
            }
            int pos = incl - cnt;   // exclusive prefix
#pragma unroll
            for (int k = 0; k < 24; ++k) {
                if (fl[k] == 0) { U_s[pos] = (unsigned short)(lane + (k << 6)); ++pos; }
            }
            mU = __builtin_amdgcn_readlane(incl, 63);
            // single wave: LDS ops in-order, no barrier needed
        }

        // issue T loads for rows g+16..g+23 (consumed 2 groups from now)
        uint2 nb[8];
#pragma unroll
        for (int k = 0; k < 8; ++k) {
            int r = g + 16 + k;
            r = (r < NS) ? r : (NS - 1);
            nb[k] = T[r * 64 + lane];
        }

#pragma unroll
        for (int q = 0; q < 8; ++q) {
            const int i = g + q;

            // prefetch used-flags for row i+1 (candidates resident in buf[q+1])
            const uint2 pn = buf[q + 1];
            const int n0 = (int)(pn.x & 0xFFFFu), n1 = (int)(pn.x >> 16);
            const int n2 = (int)(pn.y & 0xFFFFu), n3 = (int)(pn.y >> 16);
            const int g0 = used_s[n0 < NS ? n0 : 0];
            const int g1 = used_s[n1 < NS ? n1 : 0];
            const int g2 = used_s[n2 < NS ? n2 : 0];
            const int g3 = used_s[n3 < NS ? n3 : 0];

            const uint2 pc = buf[q];
            const int c0 = (int)(pc.x & 0xFFFFu), c1 = (int)(pc.x >> 16);
            const int c2 = (int)(pc.y & 0xFFFFu), c3 = (int)(pc.y >> 16);
            const bool a0 = (c0 < NS) && (f0 == 0) && (c0 != jprev);
            const bool a1 = (c1 < NS) && (f1 == 0) && (c1 != jprev);
            const bool a2 = (c2 < NS) && (f2 == 0) && (c2 != jprev);
            const bool a3 = (c3 < NS) && (f3 == 0) && (c3 != jprev);
            const unsigned long long b0 = __ballot(a0);
            const unsigned long long b1 = __ballot(a1);
            const unsigned long long b2 = __ballot(a2);
            const unsigned long long b3 = __ballot(a3);

            int j;
            if (b0)      j = __builtin_amdgcn_readlane(c0, __ffsll(b0) - 1);
            else if (b1) j = __builtin_amdgcn_readlane(c1, __ffsll(b1) - 1);
            else if (b2) j = __builtin_amdgcn_readlane(c2, __ffsll(b2) - 1);
            else if (b3) j = __builtin_amdgcn_readlane(c3, __ffsll(b3) - 1);
            else {
                // argmax over compact unused list (exact reference semantics)
                const float* __restrict__ Lr = L + (size_t)i * NS;
                float bv = -FLT_MAX; int bi = NS;
                for (int kbase = 0; kbase < mU; kbase += 512) {
                    int idx[8]; int flc[8]; float vv[8];
#pragma unroll
                    for (int c = 0; c < 8; ++c) {
                        const int k = kbase + lane + (c << 6);
                        idx[c] = (k < mU) ? (int)U_s[k] : 0;
                    }
#pragma unroll
                    for (int c = 0; c < 8; ++c) flc[c] = used_s[idx[c]];
#pragma unroll
                    for (int c = 0; c < 8; ++c) vv[c] = Lr[idx[c]];
#pragma unroll
                    for (int c = 0; c < 8; ++c) {
                        const int k = kbase + lane + (c << 6);
                        if (k < mU && flc[c] == 0 &&
                            (vv[c] > bv || (vv[c] == bv && idx[c] < bi))) {
                            bv = vv[c]; bi = idx[c];
                        }
                    }
                }
                // ---- DPP wave argmax (val desc, idx asc tiebreak) ----
                unsigned key = __float_as_uint(bv);
                key = (key & 0x80000000u) ? ~key : (key | 0x80000000u);
                const unsigned wk = wave_max_u32_dpp(key);
                const unsigned maxk =
                    (unsigned)__builtin_amdgcn_readlane((int)wk, 63);
                unsigned cand = (key == maxk) ? (unsigned)(NS - bi) : 0u;
                const unsigned wc = wave_max_u32_dpp(cand);
                const unsigned mc =
                    (unsigned)__builtin_amdgcn_readlane((int)wc, 63);
                j = NS - (int)mc;
            }
            if (lane == 0) { used_s[j] = 1; assign_s[i] = j; }
            jprev = j;
            f0 = g0; f1 = g1; f2 = g2; f3 = g3;
        }

        // rotate: waits only for loads issued ~8 rows ago (fully landed)
#pragma unroll
        for (int k = 0; k < 8; ++k) buf[k] = buf[k + 8];
#pragma unroll
        for (int k = 0; k < 8; ++k) buf[k + 8] = nb[k];
    }

    for (int k = lane; k < NS; k += 64) assign[k] = assign_s[k];
}

// ---------------- Kernel E: emit [1536][2][64] output ----------------
__global__ __launch_bounds__(128) void kE(const float* __restrict__ sat,
                                          const float* __restrict__ uav,
                                          const int* __restrict__ assign,
                                          float* __restrict__ out) {
    const int i = blockIdx.x;
    const int t = threadIdx.x;
    if (t < 64) out[(size_t)i * 128 + t] = sat[(size_t)i * DD + t];
    else        out[(size_t)i * 128 + t] = uav[(size_t)assign[i] * DD + (t - 64)];
}

extern "C" void kernel_launch(void* const* d_in, const int* in_sizes, int n_in,
                              void* d_out, int out_size, void* d_ws, size_t ws_size,
                              hipStream_t stream) {
    const float* sat = (const float*)d_in[0];
    const float* uav = (const float*)d_in[1];
    const float* W1  = (const float*)d_in[2];
    const float* b1  = (const float*)d_in[3];
    const float* W2  = (const float*)d_in[4];
    const float* b2  = (const float*)d_in[5];
    const float* W3  = (const float*)d_in[6];
    // d_in[7] = b3: sigmoid(x+b3) monotone in x — argmax unchanged.

    float* ws = (float*)d_ws;
    float* A   = ws + OFF_A;
    float* C2  = ws + OFF_C2;
    float* L   = ws + OFF_L;
    int* assign = (int*)(ws + OFF_AS);
    unsigned short* top = (unsigned short*)(ws + OFF_A);  // aliases A/C2 (dead after kB)

    hipLaunchKernelGGL(kA, dim3(NS), dim3(64), 0, stream, sat, uav, W1, b1, A, C2);
    hipLaunchKernelGGL(kB, dim3(NS / 4, NS / 256), dim3(256), 0, stream,
                       A, C2, W2, b2, W3, L);
    hipLaunchKernelGGL(kC, dim3(NS), dim3(256), 0, stream, L, top);
    hipLaunchKernelGGL(kD, dim3(1), dim3(64), 0, stream, L, top, assign);
    hipLaunchKernelGGL(kE, dim3(NS), dim3(128), 0, stream, sat, uav, assign,
                       (float*)d_out);
}